// Round 2
// baseline (7843.029 us; speedup 1.0000x reference)
//
#include <hip/hip_runtime.h>

#define B_ 512
#define T_ 256
#define F_ 8
#define H_ 128
#define BT_ (B_*T_)
#define MH_ 512

typedef __attribute__((ext_vector_type(4))) float f32x4;
typedef __attribute__((ext_vector_type(8))) __bf16 bf16x8;

// Static device scratch: W2 transposed to [n][k], bf16 bits. 512 KB.
__device__ unsigned short g_w2t[MH_*MH_];

__device__ __forceinline__ unsigned short f2bf(float f){
  unsigned int u = __float_as_uint(f);
  unsigned int r = (u + 0x7FFFu + ((u >> 16) & 1u)) >> 16;  // RNE
  return (unsigned short)r;
}

__device__ __forceinline__ float sigm(float x){
  x = fminf(fmaxf(x, -30.f), 30.f);
  return __builtin_amdgcn_rcpf(1.f + __expf(-x));
}
__device__ __forceinline__ float tanh_(float x){
  x = fminf(fmaxf(x, -15.f), 15.f);
  float e = __expf(2.f * x);
  return (e - 1.f) * __builtin_amdgcn_rcpf(e + 1.f);
}

__device__ __forceinline__ void acc2(float2& a, f32x4 w, f32x4 v){
  a.x = fmaf(w[0], v[0], a.x);
  a.y = fmaf(w[1], v[1], a.y);
  a.x = fmaf(w[2], v[2], a.x);
  a.y = fmaf(w[3], v[3], a.y);
}

struct LstmArgs {
  const float* x[3];
  const float* Wih[3];
  const float* Whh[3];
  const float* bias[3];
  const float* hw[3];
  const float* hb[3];
  float* out;
};

// One block = (head, 8-batch tile). 512 threads: thread (j = t&127, b2 = t>>7)
// owns gate rows {j, 128+j, 256+j, 384+j} (i,f,g,o for hidden unit j) and
// 2 batch elements. c stays in registers; h broadcast via LDS each step.
__global__ __launch_bounds__(512) void lstm_kernel(LstmArgs A){
  const int head   = blockIdx.x >> 6;     // 64 tiles per head
  const int batch0 = (blockIdx.x & 63) * 8;
  const float* __restrict__ xg  = A.x[head];
  const float* __restrict__ Wih = A.Wih[head];
  const float* __restrict__ Whh = A.Whh[head];
  const float* __restrict__ bs  = A.bias[head];
  const float* __restrict__ hwp = A.hw[head];
  const float hbv = A.hb[head][0];
  float* __restrict__ D = A.out + (size_t)head * BT_;

  __shared__ float hs[8 * H_];
  __shared__ float hwv[H_];

  const int t  = threadIdx.x;
  const int j  = t & 127;
  const int b2 = t >> 7;                  // 0..3 -> batches {2*b2, 2*b2+1}

  if (t < H_) hwv[t] = hwp[t];
  for (int i = t; i < 8 * H_; i += 512) hs[i] = 0.f;

  // Wih rows (8 floats each) for the 4 gates, register-resident
  f32x4 wi0 = *(const f32x4*)(Wih + j*8);            f32x4 wi1 = *(const f32x4*)(Wih + j*8 + 4);
  f32x4 wf0 = *(const f32x4*)(Wih + (H_+j)*8);       f32x4 wf1 = *(const f32x4*)(Wih + (H_+j)*8 + 4);
  f32x4 wg0 = *(const f32x4*)(Wih + (2*H_+j)*8);     f32x4 wg1 = *(const f32x4*)(Wih + (2*H_+j)*8 + 4);
  f32x4 wo0 = *(const f32x4*)(Wih + (3*H_+j)*8);     f32x4 wo1 = *(const f32x4*)(Wih + (3*H_+j)*8 + 4);
  const float bi_ = bs[j], bf_ = bs[H_+j], bg_ = bs[2*H_+j], bo_ = bs[3*H_+j];
  const float* __restrict__ wri = Whh + (size_t)j * H_;
  const float* __restrict__ wrf = Whh + (size_t)(H_   + j) * H_;
  const float* __restrict__ wrg = Whh + (size_t)(2*H_ + j) * H_;
  const float* __restrict__ wro = Whh + (size_t)(3*H_ + j) * H_;

  float c0 = 0.f, c1 = 0.f;
  __syncthreads();

  for (int ts = 0; ts < T_; ++ts){
    float2 zi[2], zf[2], zg[2], zo[2];
    #pragma unroll
    for (int q = 0; q < 2; ++q){
      zi[q].x = 0.f; zi[q].y = 0.f;  zf[q].x = 0.f; zf[q].y = 0.f;
      zg[q].x = 0.f; zg[q].y = 0.f;  zo[q].x = 0.f; zo[q].y = 0.f;
    }
    // input contribution: x_t @ Wih^T  (x read direct from global; L2-hot, broadcast)
    #pragma unroll
    for (int q = 0; q < 2; ++q){
      const float* xp = xg + (size_t)(batch0 + b2*2 + q) * (T_*F_) + ts*F_;
      f32x4 xa = *(const f32x4*)xp;
      f32x4 xb = *(const f32x4*)(xp + 4);
      acc2(zi[q], wi0, xa); acc2(zi[q], wi1, xb);
      acc2(zf[q], wf0, xa); acc2(zf[q], wf1, xb);
      acc2(zg[q], wg0, xa); acc2(zg[q], wg1, xb);
      acc2(zo[q], wo0, xa); acc2(zo[q], wo1, xb);
    }
    // recurrent contribution: h @ Whh^T
    #pragma unroll 4
    for (int k = 0; k < H_; k += 4){
      f32x4 wiv = *(const f32x4*)(wri + k);
      f32x4 wfv = *(const f32x4*)(wrf + k);
      f32x4 wgv = *(const f32x4*)(wrg + k);
      f32x4 wov = *(const f32x4*)(wro + k);
      #pragma unroll
      for (int q = 0; q < 2; ++q){
        f32x4 hv = *(const f32x4*)&hs[(b2*2 + q) * H_ + k];   // broadcast read
        acc2(zi[q], wiv, hv); acc2(zf[q], wfv, hv);
        acc2(zg[q], wgv, hv); acc2(zo[q], wov, hv);
      }
    }
    float hn0, hn1;
    {
      float Zi = zi[0].x + zi[0].y + bi_;
      float Zf = zf[0].x + zf[0].y + bf_;
      float Zg = zg[0].x + zg[0].y + bg_;
      float Zo = zo[0].x + zo[0].y + bo_;
      c0 = sigm(Zf) * c0 + sigm(Zi) * tanh_(Zg);
      hn0 = sigm(Zo) * tanh_(c0);
    }
    {
      float Zi = zi[1].x + zi[1].y + bi_;
      float Zf = zf[1].x + zf[1].y + bf_;
      float Zg = zg[1].x + zg[1].y + bg_;
      float Zo = zo[1].x + zo[1].y + bo_;
      c1 = sigm(Zf) * c1 + sigm(Zi) * tanh_(Zg);
      hn1 = sigm(Zo) * tanh_(c1);
    }
    __syncthreads();                       // all reads of old h done
    hs[(b2*2 + 0)*H_ + j] = hn0;
    hs[(b2*2 + 1)*H_ + j] = hn1;
    __syncthreads();                       // new h visible
    // D[b][ts] = h . hw + hb  (one 64-lane group per batch element)
    {
      const int bd = t >> 6;               // 0..7
      const int jj = t & 63;
      float2 h2 = *(const float2*)&hs[bd*H_ + jj*2];
      float2 w2 = *(const float2*)&hwv[jj*2];
      float p = h2.x*w2.x + h2.y*w2.y;
      p += __shfl_xor(p, 1);  p += __shfl_xor(p, 2);  p += __shfl_xor(p, 4);
      p += __shfl_xor(p, 8);  p += __shfl_xor(p, 16); p += __shfl_xor(p, 32);
      if (jj == 0) D[(size_t)(batch0 + bd) * T_ + ts] = p + hbv;
    }
  }
}

// W2 (k-major, f32) -> g_w2t (n-major, bf16)
__global__ __launch_bounds__(256) void prep_w2t(const float* __restrict__ W2){
  const int idx = blockIdx.x * 256 + threadIdx.x;   // = n*512 + k
  const int n = idx >> 9;
  const int k = idx & 511;
  g_w2t[idx] = f2bf(W2[(size_t)k * MH_ + n]);
}

// Fused MLP: h1 computed on the fly into A-fragments, h1@W2 via bf16 MFMA,
// relu+dot(W3) fused in epilogue. Block = 4 waves x 16 rows = 64 rows.
__global__ __launch_bounds__(256) void mlp_kernel(
    const float* __restrict__ Dbase,
    const float* __restrict__ W1, const float* __restrict__ b1,
    const float* __restrict__ b2, const float* __restrict__ W3,
    const float* __restrict__ b3, float* __restrict__ out)
{
  const int tid = threadIdx.x;
  const int l   = tid & 63;
  const int w   = tid >> 6;
  const int m0  = blockIdx.x * 64 + w * 16;
  const int c16 = l & 15;
  const int kb  = (l >> 4) * 8;

  const int gr = m0 + c16;                 // A-fragment row for this lane
  const float d1 = Dbase[gr];
  const float d2 = Dbase[BT_ + gr];
  const float d3 = Dbase[2*BT_ + gr];

  // A fragments: h1[row][k], lane holds k = ks*32 + kb + i (i=0..7)
  bf16x8 afr[16];
  #pragma unroll
  for (int ks = 0; ks < 16; ++ks){
    const int kg = ks*32 + kb;
    f32x4 wa0 = *(const f32x4*)(W1 + kg);          f32x4 wa1 = *(const f32x4*)(W1 + kg + 4);
    f32x4 wb0 = *(const f32x4*)(W1 + MH_ + kg);    f32x4 wb1 = *(const f32x4*)(W1 + MH_ + kg + 4);
    f32x4 wc0 = *(const f32x4*)(W1 + 2*MH_ + kg);  f32x4 wc1 = *(const f32x4*)(W1 + 2*MH_ + kg + 4);
    f32x4 bv0 = *(const f32x4*)(b1 + kg);          f32x4 bv1 = *(const f32x4*)(b1 + kg + 4);
    union { unsigned short u[8]; bf16x8 v; } au;
    #pragma unroll
    for (int i = 0; i < 4; ++i){
      float v0 = bv0[i] + d1*wa0[i] + d2*wb0[i] + d3*wc0[i];
      float v1 = bv1[i] + d1*wa1[i] + d2*wb1[i] + d3*wc1[i];
      au.u[i]     = f2bf(fmaxf(v0, 0.f));
      au.u[4 + i] = f2bf(fmaxf(v1, 0.f));
    }
    afr[ks] = au.v;
  }

  float rs[4] = {0.f, 0.f, 0.f, 0.f};      // per-lane partial row sums (4 C-rows)
  #pragma unroll 1
  for (int pass = 0; pass < 4; ++pass){    // N=512 in 4 passes of 128 cols
    f32x4 acc[8];
    #pragma unroll
    for (int tt = 0; tt < 8; ++tt){ f32x4 z = {0.f,0.f,0.f,0.f}; acc[tt] = z; }
    #pragma unroll
    for (int ks = 0; ks < 16; ++ks){
      #pragma unroll
      for (int tt = 0; tt < 8; ++tt){
        const int n = (pass*8 + tt)*16 + c16;
        const bf16x8 bfr = *(const bf16x8*)(g_w2t + (size_t)n * MH_ + ks*32 + kb);
        acc[tt] = __builtin_amdgcn_mfma_f32_16x16x32_bf16(afr[ks], bfr, acc[tt], 0, 0, 0);
      }
    }
    #pragma unroll
    for (int tt = 0; tt < 8; ++tt){
      const int n = (pass*8 + tt)*16 + c16;
      const float b2v = b2[n];
      const float w3v = W3[n];
      #pragma unroll
      for (int r = 0; r < 4; ++r)
        rs[r] += fmaxf(acc[tt][r] + b2v, 0.f) * w3v;
    }
  }
  // reduce across the 16 lanes (c16 bits) sharing the same C-rows
  #pragma unroll
  for (int r = 0; r < 4; ++r){
    rs[r] += __shfl_xor(rs[r], 1);
    rs[r] += __shfl_xor(rs[r], 2);
    rs[r] += __shfl_xor(rs[r], 4);
    rs[r] += __shfl_xor(rs[r], 8);
  }
  if (c16 == 0){
    const float bv = b3[0];
    const int row = m0 + (l >> 4) * 4;     // C layout: row = (l>>4)*4 + r
    #pragma unroll
    for (int r = 0; r < 4; ++r)
      out[3*BT_ + row + r] = rs[r] + bv;
  }
}

extern "C" void kernel_launch(void* const* d_in, const int* in_sizes, int n_in,
                              void* d_out, int out_size, void* d_ws, size_t ws_size,
                              hipStream_t stream){
  LstmArgs A;
  for (int i = 0; i < 3; ++i){
    A.x[i]    = (const float*)d_in[i];
    A.Wih[i]  = (const float*)d_in[3 + i*5 + 0];
    A.Whh[i]  = (const float*)d_in[3 + i*5 + 1];
    A.bias[i] = (const float*)d_in[3 + i*5 + 2];
    A.hw[i]   = (const float*)d_in[3 + i*5 + 3];
    A.hb[i]   = (const float*)d_in[3 + i*5 + 4];
  }
  A.out = (float*)d_out;

  prep_w2t<<<dim3(1024), dim3(256), 0, stream>>>((const float*)d_in[20]);
  lstm_kernel<<<dim3(192), dim3(512), 0, stream>>>(A);
  mlp_kernel<<<dim3(2048), dim3(256), 0, stream>>>((const float*)d_out,
      (const float*)d_in[18], (const float*)d_in[19],
      (const float*)d_in[21], (const float*)d_in[22], (const float*)d_in[23],
      (float*)d_out);
}

// Round 3
// 7815.798 us; speedup vs baseline: 1.0035x; 1.0035x over previous
//
#include <hip/hip_runtime.h>

#define B_ 512
#define T_ 256
#define F_ 8
#define H_ 128
#define BT_ (B_*T_)
#define MH_ 512

typedef __attribute__((ext_vector_type(4))) float f32x4;
typedef __attribute__((ext_vector_type(8))) __bf16 bf16x8;

// Static device scratch: W2 transposed to [n][k], bf16 bits. 512 KB.
__device__ unsigned short g_w2t[MH_*MH_];

__device__ __forceinline__ unsigned short f2bf(float f){
  unsigned int u = __float_as_uint(f);
  unsigned int r = (u + 0x7FFFu + ((u >> 16) & 1u)) >> 16;  // RNE
  return (unsigned short)r;
}

__device__ __forceinline__ float sigm(float x){
  x = fminf(fmaxf(x, -30.f), 30.f);
  return __builtin_amdgcn_rcpf(1.f + __expf(-x));
}
__device__ __forceinline__ float tanh_(float x){
  x = fminf(fmaxf(x, -15.f), 15.f);
  float e = __expf(2.f * x);
  return (e - 1.f) * __builtin_amdgcn_rcpf(e + 1.f);
}

__device__ __forceinline__ void acc2(float2& a, f32x4 w, f32x4 v){
  a.x = fmaf(w[0], v[0], a.x);
  a.y = fmaf(w[1], v[1], a.y);
  a.x = fmaf(w[2], v[2], a.x);
  a.y = fmaf(w[3], v[3], a.y);
}

struct LstmArgs {
  const float* x[3];
  const float* Wih[3];
  const float* Whh[3];
  const float* bias[3];
  const float* hw[3];
  const float* hb[3];
  float* out;
};

// One block = (head, 8-batch tile). 512 threads: thread (j = t&127, b2 = t>>7)
// owns gate rows {j, 128+j, 256+j, 384+j} (i,f,g,o for hidden unit j) and
// 2 batch elements. c stays in registers; h broadcast via LDS each step.
__global__ __launch_bounds__(512) void lstm_kernel(LstmArgs A){
  const int head   = blockIdx.x >> 6;     // 64 tiles per head
  const int batch0 = (blockIdx.x & 63) * 8;
  const float* __restrict__ xg  = A.x[head];
  const float* __restrict__ Wih = A.Wih[head];
  const float* __restrict__ Whh = A.Whh[head];
  const float* __restrict__ bs  = A.bias[head];
  const float* __restrict__ hwp = A.hw[head];
  const float hbv = A.hb[head][0];
  float* __restrict__ D = A.out + (size_t)head * BT_;

  __shared__ float hs[8 * H_];
  __shared__ float hwv[H_];

  const int t  = threadIdx.x;
  const int j  = t & 127;
  const int b2 = t >> 7;                  // 0..3 -> batches {2*b2, 2*b2+1}

  if (t < H_) hwv[t] = hwp[t];
  for (int i = t; i < 8 * H_; i += 512) hs[i] = 0.f;

  // Wih rows (8 floats each) for the 4 gates, register-resident
  f32x4 wi0 = *(const f32x4*)(Wih + j*8);            f32x4 wi1 = *(const f32x4*)(Wih + j*8 + 4);
  f32x4 wf0 = *(const f32x4*)(Wih + (H_+j)*8);       f32x4 wf1 = *(const f32x4*)(Wih + (H_+j)*8 + 4);
  f32x4 wg0 = *(const f32x4*)(Wih + (2*H_+j)*8);     f32x4 wg1 = *(const f32x4*)(Wih + (2*H_+j)*8 + 4);
  f32x4 wo0 = *(const f32x4*)(Wih + (3*H_+j)*8);     f32x4 wo1 = *(const f32x4*)(Wih + (3*H_+j)*8 + 4);
  const float bi_ = bs[j], bf_ = bs[H_+j], bg_ = bs[2*H_+j], bo_ = bs[3*H_+j];
  const float* __restrict__ wri = Whh + (size_t)j * H_;
  const float* __restrict__ wrf = Whh + (size_t)(H_   + j) * H_;
  const float* __restrict__ wrg = Whh + (size_t)(2*H_ + j) * H_;
  const float* __restrict__ wro = Whh + (size_t)(3*H_ + j) * H_;

  float c0 = 0.f, c1 = 0.f;
  __syncthreads();

  for (int ts = 0; ts < T_; ++ts){
    float2 zi[2], zf[2], zg[2], zo[2];
    #pragma unroll
    for (int q = 0; q < 2; ++q){
      zi[q].x = 0.f; zi[q].y = 0.f;  zf[q].x = 0.f; zf[q].y = 0.f;
      zg[q].x = 0.f; zg[q].y = 0.f;  zo[q].x = 0.f; zo[q].y = 0.f;
    }
    // input contribution: x_t @ Wih^T  (x read direct from global; L2-hot, broadcast)
    #pragma unroll
    for (int q = 0; q < 2; ++q){
      const float* xp = xg + (size_t)(batch0 + b2*2 + q) * (T_*F_) + ts*F_;
      f32x4 xa = *(const f32x4*)xp;
      f32x4 xb = *(const f32x4*)(xp + 4);
      acc2(zi[q], wi0, xa); acc2(zi[q], wi1, xb);
      acc2(zf[q], wf0, xa); acc2(zf[q], wf1, xb);
      acc2(zg[q], wg0, xa); acc2(zg[q], wg1, xb);
      acc2(zo[q], wo0, xa); acc2(zo[q], wo1, xb);
    }
    // recurrent contribution: h @ Whh^T
    #pragma unroll 4
    for (int k = 0; k < H_; k += 4){
      f32x4 wiv = *(const f32x4*)(wri + k);
      f32x4 wfv = *(const f32x4*)(wrf + k);
      f32x4 wgv = *(const f32x4*)(wrg + k);
      f32x4 wov = *(const f32x4*)(wro + k);
      #pragma unroll
      for (int q = 0; q < 2; ++q){
        f32x4 hv = *(const f32x4*)&hs[(b2*2 + q) * H_ + k];   // broadcast read
        acc2(zi[q], wiv, hv); acc2(zf[q], wfv, hv);
        acc2(zg[q], wgv, hv); acc2(zo[q], wov, hv);
      }
    }
    float hn0, hn1;
    {
      float Zi = zi[0].x + zi[0].y + bi_;
      float Zf = zf[0].x + zf[0].y + bf_;
      float Zg = zg[0].x + zg[0].y + bg_;
      float Zo = zo[0].x + zo[0].y + bo_;
      c0 = sigm(Zf) * c0 + sigm(Zi) * tanh_(Zg);
      hn0 = sigm(Zo) * tanh_(c0);
    }
    {
      float Zi = zi[1].x + zi[1].y + bi_;
      float Zf = zf[1].x + zf[1].y + bf_;
      float Zg = zg[1].x + zg[1].y + bg_;
      float Zo = zo[1].x + zo[1].y + bo_;
      c1 = sigm(Zf) * c1 + sigm(Zi) * tanh_(Zg);
      hn1 = sigm(Zo) * tanh_(c1);
    }
    __syncthreads();                       // all reads of old h done
    hs[(b2*2 + 0)*H_ + j] = hn0;
    hs[(b2*2 + 1)*H_ + j] = hn1;
    __syncthreads();                       // new h visible
    // D[b][ts] = h . hw + hb  (one 64-lane group per batch element)
    {
      const int bd = t >> 6;               // 0..7
      const int jj = t & 63;
      float2 h2 = *(const float2*)&hs[bd*H_ + jj*2];
      float2 w2 = *(const float2*)&hwv[jj*2];
      float p = h2.x*w2.x + h2.y*w2.y;
      p += __shfl_xor(p, 1);  p += __shfl_xor(p, 2);  p += __shfl_xor(p, 4);
      p += __shfl_xor(p, 8);  p += __shfl_xor(p, 16); p += __shfl_xor(p, 32);
      if (jj == 0) D[(size_t)(batch0 + bd) * T_ + ts] = p + hbv;
    }
  }
}

// W2 (k-major, f32) -> g_w2t (n-major, bf16)
__global__ __launch_bounds__(256) void prep_w2t(const float* __restrict__ W2){
  const int idx = blockIdx.x * 256 + threadIdx.x;   // = n*512 + k
  const int n = idx >> 9;
  const int k = idx & 511;
  g_w2t[idx] = f2bf(W2[(size_t)k * MH_ + n]);
}

// Fused MLP: h1 computed on the fly into A-fragments, h1@W2 via bf16 MFMA,
// relu+dot(W3) fused in epilogue. Block = 4 waves x 16 rows = 64 rows.
__global__ __launch_bounds__(256) void mlp_kernel(
    const float* __restrict__ Dbase,
    const float* __restrict__ W1, const float* __restrict__ b1,
    const float* __restrict__ b2, const float* __restrict__ W3,
    const float* __restrict__ b3, float* __restrict__ out)
{
  const int tid = threadIdx.x;
  const int l   = tid & 63;
  const int w   = tid >> 6;
  const int m0  = blockIdx.x * 64 + w * 16;
  const int c16 = l & 15;
  const int kb  = (l >> 4) * 8;

  const int gr = m0 + c16;                 // A-fragment row for this lane
  const float d1 = Dbase[gr];
  const float d2 = Dbase[BT_ + gr];
  const float d3 = Dbase[2*BT_ + gr];

  // A fragments: h1[row][k], lane holds k = ks*32 + kb + i (i=0..7)
  bf16x8 afr[16];
  #pragma unroll
  for (int ks = 0; ks < 16; ++ks){
    const int kg = ks*32 + kb;
    f32x4 wa0 = *(const f32x4*)(W1 + kg);          f32x4 wa1 = *(const f32x4*)(W1 + kg + 4);
    f32x4 wb0 = *(const f32x4*)(W1 + MH_ + kg);    f32x4 wb1 = *(const f32x4*)(W1 + MH_ + kg + 4);
    f32x4 wc0 = *(const f32x4*)(W1 + 2*MH_ + kg);  f32x4 wc1 = *(const f32x4*)(W1 + 2*MH_ + kg + 4);
    f32x4 bv0 = *(const f32x4*)(b1 + kg);          f32x4 bv1 = *(const f32x4*)(b1 + kg + 4);
    union { unsigned short u[8]; bf16x8 v; } au;
    #pragma unroll
    for (int i = 0; i < 4; ++i){
      float v0 = bv0[i] + d1*wa0[i] + d2*wb0[i] + d3*wc0[i];
      float v1 = bv1[i] + d1*wa1[i] + d2*wb1[i] + d3*wc1[i];
      au.u[i]     = f2bf(fmaxf(v0, 0.f));
      au.u[4 + i] = f2bf(fmaxf(v1, 0.f));
    }
    afr[ks] = au.v;
  }

  float rs[4] = {0.f, 0.f, 0.f, 0.f};      // per-lane partial row sums (4 C-rows)
  #pragma unroll 1
  for (int pass = 0; pass < 4; ++pass){    // N=512 in 4 passes of 128 cols
    f32x4 acc[8];
    #pragma unroll
    for (int tt = 0; tt < 8; ++tt){ f32x4 z = {0.f,0.f,0.f,0.f}; acc[tt] = z; }
    #pragma unroll
    for (int ks = 0; ks < 16; ++ks){
      #pragma unroll
      for (int tt = 0; tt < 8; ++tt){
        const int n = (pass*8 + tt)*16 + c16;
        const bf16x8 bfr = *(const bf16x8*)(g_w2t + (size_t)n * MH_ + ks*32 + kb);
        acc[tt] = __builtin_amdgcn_mfma_f32_16x16x32_bf16(afr[ks], bfr, acc[tt], 0, 0, 0);
      }
    }
    #pragma unroll
    for (int tt = 0; tt < 8; ++tt){
      const int n = (pass*8 + tt)*16 + c16;
      const float b2v = b2[n];
      const float w3v = W3[n];
      #pragma unroll
      for (int r = 0; r < 4; ++r)
        rs[r] += fmaxf(acc[tt][r] + b2v, 0.f) * w3v;
    }
  }
  // reduce across the 16 lanes (c16 bits) sharing the same C-rows
  #pragma unroll
  for (int r = 0; r < 4; ++r){
    rs[r] += __shfl_xor(rs[r], 1);
    rs[r] += __shfl_xor(rs[r], 2);
    rs[r] += __shfl_xor(rs[r], 4);
    rs[r] += __shfl_xor(rs[r], 8);
  }
  if (c16 == 0){
    const float bv = b3[0];
    const int row = m0 + (l >> 4) * 4;     // C layout: row = (l>>4)*4 + r
    #pragma unroll
    for (int r = 0; r < 4; ++r)
      out[3*BT_ + row + r] = rs[r] + bv;
  }
}

extern "C" void kernel_launch(void* const* d_in, const int* in_sizes, int n_in,
                              void* d_out, int out_size, void* d_ws, size_t ws_size,
                              hipStream_t stream){
  LstmArgs A;
  for (int i = 0; i < 3; ++i){
    A.x[i]    = (const float*)d_in[i];
    A.Wih[i]  = (const float*)d_in[3 + i*5 + 0];
    A.Whh[i]  = (const float*)d_in[3 + i*5 + 1];
    A.bias[i] = (const float*)d_in[3 + i*5 + 2];
    A.hw[i]   = (const float*)d_in[3 + i*5 + 3];
    A.hb[i]   = (const float*)d_in[3 + i*5 + 4];
  }
  A.out = (float*)d_out;

  prep_w2t<<<dim3(1024), dim3(256), 0, stream>>>((const float*)d_in[20]);
  lstm_kernel<<<dim3(192), dim3(512), 0, stream>>>(A);
  mlp_kernel<<<dim3(2048), dim3(256), 0, stream>>>((const float*)d_out,
      (const float*)d_in[18], (const float*)d_in[19],
      (const float*)d_in[21], (const float*)d_in[22], (const float*)d_in[23],
      (float*)d_out);
}

// Round 4
// 849.108 us; speedup vs baseline: 9.2368x; 9.2047x over previous
//
#include <hip/hip_runtime.h>

#define B_ 512
#define T_ 256
#define F_ 8
#define H_ 128
#define BT_ (B_*T_)
#define MH_ 512

typedef __attribute__((ext_vector_type(4))) float f32x4;
typedef __attribute__((ext_vector_type(8))) __bf16 bf16x8;

// Static device scratch
__device__ unsigned short g_w2t[MH_*MH_];            // MLP W2^T bf16, [n][k]
__device__ unsigned short g_whh[3][512][128];        // packed Whh bf16, [head][pc][k]
__device__ unsigned short g_wih[3][512][32];         // packed Wih bf16, k>=8 zero
__device__ unsigned short g_xbf[3][B_*T_*F_];        // x in bf16, same (B,T,F) layout

__device__ __forceinline__ unsigned short f2bf(float f){
  unsigned int u = __float_as_uint(f);
  unsigned int r = (u + 0x7FFFu + ((u >> 16) & 1u)) >> 16;  // RNE
  return (unsigned short)r;
}

__device__ __forceinline__ float sigm(float x){
  x = fminf(fmaxf(x, -30.f), 30.f);
  return __builtin_amdgcn_rcpf(1.f + __expf(-x));
}
__device__ __forceinline__ float tanh_(float x){
  x = fminf(fmaxf(x, -15.f), 15.f);
  float e = __expf(2.f * x);
  return (e - 1.f) * __builtin_amdgcn_rcpf(e + 1.f);
}

struct LstmArgs {
  const float* x[3];
  const float* Wih[3];
  const float* Whh[3];
  const float* bias[3];
  const float* hw[3];
  const float* hb[3];
  float* out;
};

// Pack Whh/Wih into MFMA column order + convert x to bf16.
// Column packing: pc = w*64 + g*16 + s  ->  unit u = w*16+s, gate g (i,f,g,o),
// original weight row = g*128 + u. So wave w's 4 N-tiles are the 4 gates of
// its 16 units, and i/f/g/o of one unit land in the SAME lane (l&15 = s).
__global__ __launch_bounds__(256) void prep_lstm(LstmArgs A){
  const int NW = 3*512*128;      // whh elems
  const int NI = 3*512*32;       // wih elems (zero-padded)
  const int NX = 3*B_*T_*F_;     // x elems
  for (int i = blockIdx.x*256 + threadIdx.x; i < NW+NI+NX; i += gridDim.x*256){
    if (i < NW){
      int head = i >> 16;                  // /65536
      int r = i & 65535;
      int pc = r >> 7, k = r & 127;
      int w = pc >> 6, g = (pc >> 4) & 3, s = pc & 15;
      int row = g*128 + w*16 + s;
      g_whh[head][pc][k] = f2bf(A.Whh[head][row*H_ + k]);
    } else if (i < NW + NI){
      int j = i - NW;
      int head = j >> 14;                  // /16384
      int r = j & 16383;
      int pc = r >> 5, k = r & 31;
      int w = pc >> 6, g = (pc >> 4) & 3, s = pc & 15;
      int row = g*128 + w*16 + s;
      g_wih[head][pc][k] = (k < 8) ? f2bf(A.Wih[head][row*F_ + k]) : (unsigned short)0;
    } else {
      int j = i - NW - NI;
      int head = j >> 20;                  // /1048576
      int r = j & 1048575;
      g_xbf[head][r] = f2bf(A.x[head][r]);
    }
  }
}

// MFMA LSTM: block = (head, 16-batch tile), 8 waves. Wave w owns gate-columns
// pc in [64w, 64w+64) = units [16w,16w+16) x 4 gates. Whh/Wih B-fragments are
// register-resident for the whole T loop; h round-trips through LDS each step
// (bf16 copy feeds next step's A-frags, f32 copy feeds the head-dot).
__global__ __launch_bounds__(512) void lstm_mfma_kernel(LstmArgs A){
  const int head   = blockIdx.x >> 5;          // 32 batch tiles per head
  const int batch0 = (blockIdx.x & 31) * 16;
  const int tid = threadIdx.x;
  const int w   = tid >> 6;
  const int l   = tid & 63;
  const int c16 = l & 15;
  const int kb  = (l >> 4) * 8;                // k-offset this lane supplies

  const float* __restrict__ bs  = A.bias[head];
  const float* __restrict__ hwp = A.hw[head];
  const float hbv = A.hb[head][0];
  float* __restrict__ D = A.out + (size_t)head * BT_;

  // B-fragments, register-resident: bh[gate][kstep], bx[gate]
  bf16x8 bh[4][4];
  bf16x8 bx[4];
  #pragma unroll
  for (int g = 0; g < 4; ++g){
    const int pc = w*64 + g*16 + c16;
    #pragma unroll
    for (int kk = 0; kk < 4; ++kk)
      bh[g][kk] = *(const bf16x8*)&g_whh[head][pc][kk*32 + kb];
    bx[g] = *(const bf16x8*)&g_wih[head][pc][kb];
  }

  // biases for this lane's unit
  const int u = w*16 + c16;
  const float bi_ = bs[u], bf_ = bs[H_+u], bg_ = bs[2*H_+u], bo_ = bs[3*H_+u];

  // head-dot weights: thread covers units (tid&31)*4 .. +3
  const f32x4 hw4 = *(const f32x4*)&hwp[(tid & 31) * 4];

  __shared__ __align__(16) unsigned short h_bf[16][136];  // padded: 2-way-free banks
  __shared__ float h_f32[16][132];

  for (int i = tid; i < 16*136; i += 512) ((unsigned short*)h_bf)[i] = 0;

  float cst[4] = {0.f, 0.f, 0.f, 0.f};
  const unsigned short* __restrict__ xrow =
      &g_xbf[head][(size_t)(batch0 + c16) * (T_*F_)];

  __syncthreads();

  for (int ts = 0; ts < T_; ++ts){
    // A-frags: h (bf16) from LDS; x from global (lanes 0-15 supply k<8, rest 0)
    bf16x8 ah[4];
    #pragma unroll
    for (int kk = 0; kk < 4; ++kk)
      ah[kk] = *(const bf16x8*)&h_bf[c16][kk*32 + kb];
    bf16x8 ax = {};
    if (l < 16) ax = *(const bf16x8*)(xrow + ts*F_);

    f32x4 acc[4];
    const f32x4 z4 = {0.f, 0.f, 0.f, 0.f};
    #pragma unroll
    for (int g = 0; g < 4; ++g)
      acc[g] = __builtin_amdgcn_mfma_f32_16x16x32_bf16(ax, bx[g], z4, 0, 0, 0);
    #pragma unroll
    for (int kk = 0; kk < 4; ++kk){
      #pragma unroll
      for (int g = 0; g < 4; ++g)
        acc[g] = __builtin_amdgcn_mfma_f32_16x16x32_bf16(ah[kk], bh[g][kk], acc[g], 0, 0, 0);
    }

    // cell update: 4 cells/lane (batch rows (l>>4)*4 + r, unit u)
    float hn[4];
    #pragma unroll
    for (int r = 0; r < 4; ++r){
      const float Zi = acc[0][r] + bi_;
      const float Zf = acc[1][r] + bf_;
      const float Zg = acc[2][r] + bg_;
      const float Zo = acc[3][r] + bo_;
      cst[r] = sigm(Zf) * cst[r] + sigm(Zi) * tanh_(Zg);
      hn[r]  = sigm(Zo) * tanh_(cst[r]);
    }

    __syncthreads();                           // all reads of old h done
    #pragma unroll
    for (int r = 0; r < 4; ++r){
      const int b = (l >> 4) * 4 + r;
      h_bf[b][u]  = f2bf(hn[r]);
      h_f32[b][u] = hn[r];
    }
    __syncthreads();                           // new h visible

    // D[b][ts] = h . hw + hb  (32 threads per batch, f32 h)
    {
      const int b = tid >> 5;                  // 0..15
      const int q = tid & 31;
      const f32x4 hv = *(const f32x4*)&h_f32[b][q*4];
      float p = hv[0]*hw4[0] + hv[1]*hw4[1] + hv[2]*hw4[2] + hv[3]*hw4[3];
      p += __shfl_xor(p, 1);  p += __shfl_xor(p, 2);  p += __shfl_xor(p, 4);
      p += __shfl_xor(p, 8);  p += __shfl_xor(p, 16);
      if (q == 0) D[(size_t)(batch0 + b) * T_ + ts] = p + hbv;
    }
  }
}

// W2 (k-major, f32) -> g_w2t (n-major, bf16)
__global__ __launch_bounds__(256) void prep_w2t(const float* __restrict__ W2){
  const int idx = blockIdx.x * 256 + threadIdx.x;   // = n*512 + k
  const int n = idx >> 9;
  const int k = idx & 511;
  g_w2t[idx] = f2bf(W2[(size_t)k * MH_ + n]);
}

// Fused MLP: h1 computed on the fly into A-fragments, h1@W2 via bf16 MFMA,
// relu+dot(W3) fused in epilogue. Block = 4 waves x 16 rows = 64 rows.
__global__ __launch_bounds__(256) void mlp_kernel(
    const float* __restrict__ Dbase,
    const float* __restrict__ W1, const float* __restrict__ b1,
    const float* __restrict__ b2, const float* __restrict__ W3,
    const float* __restrict__ b3, float* __restrict__ out)
{
  const int tid = threadIdx.x;
  const int l   = tid & 63;
  const int w   = tid >> 6;
  const int m0  = blockIdx.x * 64 + w * 16;
  const int c16 = l & 15;
  const int kb  = (l >> 4) * 8;

  const int gr = m0 + c16;                 // A-fragment row for this lane
  const float d1 = Dbase[gr];
  const float d2 = Dbase[BT_ + gr];
  const float d3 = Dbase[2*BT_ + gr];

  // A fragments: h1[row][k], lane holds k = ks*32 + kb + i (i=0..7)
  bf16x8 afr[16];
  #pragma unroll
  for (int ks = 0; ks < 16; ++ks){
    const int kg = ks*32 + kb;
    f32x4 wa0 = *(const f32x4*)(W1 + kg);          f32x4 wa1 = *(const f32x4*)(W1 + kg + 4);
    f32x4 wb0 = *(const f32x4*)(W1 + MH_ + kg);    f32x4 wb1 = *(const f32x4*)(W1 + MH_ + kg + 4);
    f32x4 wc0 = *(const f32x4*)(W1 + 2*MH_ + kg);  f32x4 wc1 = *(const f32x4*)(W1 + 2*MH_ + kg + 4);
    f32x4 bv0 = *(const f32x4*)(b1 + kg);          f32x4 bv1 = *(const f32x4*)(b1 + kg + 4);
    union { unsigned short u[8]; bf16x8 v; } au;
    #pragma unroll
    for (int i = 0; i < 4; ++i){
      float v0 = bv0[i] + d1*wa0[i] + d2*wb0[i] + d3*wc0[i];
      float v1 = bv1[i] + d1*wa1[i] + d2*wb1[i] + d3*wc1[i];
      au.u[i]     = f2bf(fmaxf(v0, 0.f));
      au.u[4 + i] = f2bf(fmaxf(v1, 0.f));
    }
    afr[ks] = au.v;
  }

  float rs[4] = {0.f, 0.f, 0.f, 0.f};      // per-lane partial row sums (4 C-rows)
  #pragma unroll 1
  for (int pass = 0; pass < 4; ++pass){    // N=512 in 4 passes of 128 cols
    f32x4 acc[8];
    #pragma unroll
    for (int tt = 0; tt < 8; ++tt){ f32x4 z = {0.f,0.f,0.f,0.f}; acc[tt] = z; }
    #pragma unroll
    for (int ks = 0; ks < 16; ++ks){
      #pragma unroll
      for (int tt = 0; tt < 8; ++tt){
        const int n = (pass*8 + tt)*16 + c16;
        const bf16x8 bfr = *(const bf16x8*)(g_w2t + (size_t)n * MH_ + ks*32 + kb);
        acc[tt] = __builtin_amdgcn_mfma_f32_16x16x32_bf16(afr[ks], bfr, acc[tt], 0, 0, 0);
      }
    }
    #pragma unroll
    for (int tt = 0; tt < 8; ++tt){
      const int n = (pass*8 + tt)*16 + c16;
      const float b2v = b2[n];
      const float w3v = W3[n];
      #pragma unroll
      for (int r = 0; r < 4; ++r)
        rs[r] += fmaxf(acc[tt][r] + b2v, 0.f) * w3v;
    }
  }
  // reduce across the 16 lanes (c16 bits) sharing the same C-rows
  #pragma unroll
  for (int r = 0; r < 4; ++r){
    rs[r] += __shfl_xor(rs[r], 1);
    rs[r] += __shfl_xor(rs[r], 2);
    rs[r] += __shfl_xor(rs[r], 4);
    rs[r] += __shfl_xor(rs[r], 8);
  }
  if (c16 == 0){
    const float bv = b3[0];
    const int row = m0 + (l >> 4) * 4;     // C layout: row = (l>>4)*4 + r
    #pragma unroll
    for (int r = 0; r < 4; ++r)
      out[3*BT_ + row + r] = rs[r] + bv;
  }
}

extern "C" void kernel_launch(void* const* d_in, const int* in_sizes, int n_in,
                              void* d_out, int out_size, void* d_ws, size_t ws_size,
                              hipStream_t stream){
  LstmArgs A;
  for (int i = 0; i < 3; ++i){
    A.x[i]    = (const float*)d_in[i];
    A.Wih[i]  = (const float*)d_in[3 + i*5 + 0];
    A.Whh[i]  = (const float*)d_in[3 + i*5 + 1];
    A.bias[i] = (const float*)d_in[3 + i*5 + 2];
    A.hw[i]   = (const float*)d_in[3 + i*5 + 3];
    A.hb[i]   = (const float*)d_in[3 + i*5 + 4];
  }
  A.out = (float*)d_out;

  prep_w2t<<<dim3(1024), dim3(256), 0, stream>>>((const float*)d_in[20]);
  prep_lstm<<<dim3(2048), dim3(256), 0, stream>>>(A);
  lstm_mfma_kernel<<<dim3(96), dim3(512), 0, stream>>>(A);
  mlp_kernel<<<dim3(2048), dim3(256), 0, stream>>>((const float*)d_out,
      (const float*)d_in[18], (const float*)d_in[19],
      (const float*)d_in[21], (const float*)d_in[22], (const float*)d_in[23],
      (float*)d_out);
}

// Round 5
// 576.438 us; speedup vs baseline: 13.6060x; 1.4730x over previous
//
#include <hip/hip_runtime.h>

#define B_ 512
#define T_ 256
#define F_ 8
#define H_ 128
#define BT_ (B_*T_)
#define MH_ 512

typedef __attribute__((ext_vector_type(4))) float f32x4;
typedef __attribute__((ext_vector_type(8))) __bf16 bf16x8;

// Static device scratch
// g_w2t: W2^T bf16, row n holds k-elems PRE-SWIZZLED: elem (k ^ ((n&7)<<3)).
// The LDS staging copy is linear, the ds_read applies the same XOR -> bank-even.
__device__ unsigned short g_w2t[MH_*MH_];
__device__ unsigned short g_whh[3][512][128];        // packed Whh bf16, [head][pc][k]
__device__ unsigned short g_wih[3][512][32];         // packed Wih bf16, k>=8 zero
__device__ unsigned short g_xbf[3][B_*T_*F_];        // x in bf16, same (B,T,F) layout

__device__ __forceinline__ unsigned short f2bf(float f){
  unsigned int u = __float_as_uint(f);
  unsigned int r = (u + 0x7FFFu + ((u >> 16) & 1u)) >> 16;  // RNE
  return (unsigned short)r;
}

__device__ __forceinline__ float sigm(float x){
  x = fminf(fmaxf(x, -30.f), 30.f);
  return __builtin_amdgcn_rcpf(1.f + __expf(-x));
}
__device__ __forceinline__ float tanh_(float x){
  x = fminf(fmaxf(x, -15.f), 15.f);
  float e = __expf(2.f * x);
  return (e - 1.f) * __builtin_amdgcn_rcpf(e + 1.f);
}

struct LstmArgs {
  const float* x[3];
  const float* Wih[3];
  const float* Whh[3];
  const float* bias[3];
  const float* hw[3];
  const float* hb[3];
  float* out;
};

// Pack Whh/Wih into MFMA column order + convert x to bf16.
__global__ __launch_bounds__(256) void prep_lstm(LstmArgs A){
  const int NW = 3*512*128;      // whh elems
  const int NI = 3*512*32;       // wih elems (zero-padded)
  const int NX = 3*B_*T_*F_;     // x elems
  for (int i = blockIdx.x*256 + threadIdx.x; i < NW+NI+NX; i += gridDim.x*256){
    if (i < NW){
      int head = i >> 16;
      int r = i & 65535;
      int pc = r >> 7, k = r & 127;
      int w = pc >> 6, g = (pc >> 4) & 3, s = pc & 15;
      int row = g*128 + w*16 + s;
      g_whh[head][pc][k] = f2bf(A.Whh[head][row*H_ + k]);
    } else if (i < NW + NI){
      int j = i - NW;
      int head = j >> 14;
      int r = j & 16383;
      int pc = r >> 5, k = r & 31;
      int w = pc >> 6, g = (pc >> 4) & 3, s = pc & 15;
      int row = g*128 + w*16 + s;
      g_wih[head][pc][k] = (k < 8) ? f2bf(A.Wih[head][row*F_ + k]) : (unsigned short)0;
    } else {
      int j = i - NW - NI;
      int head = j >> 20;
      int r = j & 1048575;
      g_xbf[head][r] = f2bf(A.x[head][r]);
    }
  }
}

// MFMA LSTM (unchanged from round 4): block = (head, 16-batch tile), 8 waves.
__global__ __launch_bounds__(512) void lstm_mfma_kernel(LstmArgs A){
  const int head   = blockIdx.x >> 5;
  const int batch0 = (blockIdx.x & 31) * 16;
  const int tid = threadIdx.x;
  const int w   = tid >> 6;
  const int l   = tid & 63;
  const int c16 = l & 15;
  const int kb  = (l >> 4) * 8;

  const float* __restrict__ bs  = A.bias[head];
  const float* __restrict__ hwp = A.hw[head];
  const float hbv = A.hb[head][0];
  float* __restrict__ D = A.out + (size_t)head * BT_;

  bf16x8 bh[4][4];
  bf16x8 bx[4];
  #pragma unroll
  for (int g = 0; g < 4; ++g){
    const int pc = w*64 + g*16 + c16;
    #pragma unroll
    for (int kk = 0; kk < 4; ++kk)
      bh[g][kk] = *(const bf16x8*)&g_whh[head][pc][kk*32 + kb];
    bx[g] = *(const bf16x8*)&g_wih[head][pc][kb];
  }

  const int u = w*16 + c16;
  const float bi_ = bs[u], bf_ = bs[H_+u], bg_ = bs[2*H_+u], bo_ = bs[3*H_+u];
  const f32x4 hw4 = *(const f32x4*)&hwp[(tid & 31) * 4];

  __shared__ __align__(16) unsigned short h_bf[16][136];
  __shared__ float h_f32[16][132];

  for (int i = tid; i < 16*136; i += 512) ((unsigned short*)h_bf)[i] = 0;

  float cst[4] = {0.f, 0.f, 0.f, 0.f};
  const unsigned short* __restrict__ xrow =
      &g_xbf[head][(size_t)(batch0 + c16) * (T_*F_)];

  __syncthreads();

  for (int ts = 0; ts < T_; ++ts){
    bf16x8 ah[4];
    #pragma unroll
    for (int kk = 0; kk < 4; ++kk)
      ah[kk] = *(const bf16x8*)&h_bf[c16][kk*32 + kb];
    bf16x8 ax = {};
    if (l < 16) ax = *(const bf16x8*)(xrow + ts*F_);

    f32x4 acc[4];
    const f32x4 z4 = {0.f, 0.f, 0.f, 0.f};
    #pragma unroll
    for (int g = 0; g < 4; ++g)
      acc[g] = __builtin_amdgcn_mfma_f32_16x16x32_bf16(ax, bx[g], z4, 0, 0, 0);
    #pragma unroll
    for (int kk = 0; kk < 4; ++kk){
      #pragma unroll
      for (int g = 0; g < 4; ++g)
        acc[g] = __builtin_amdgcn_mfma_f32_16x16x32_bf16(ah[kk], bh[g][kk], acc[g], 0, 0, 0);
    }

    float hn[4];
    #pragma unroll
    for (int r = 0; r < 4; ++r){
      const float Zi = acc[0][r] + bi_;
      const float Zf = acc[1][r] + bf_;
      const float Zg = acc[2][r] + bg_;
      const float Zo = acc[3][r] + bo_;
      cst[r] = sigm(Zf) * cst[r] + sigm(Zi) * tanh_(Zg);
      hn[r]  = sigm(Zo) * tanh_(cst[r]);
    }

    __syncthreads();
    #pragma unroll
    for (int r = 0; r < 4; ++r){
      const int b = (l >> 4) * 4 + r;
      h_bf[b][u]  = f2bf(hn[r]);
      h_f32[b][u] = hn[r];
    }
    __syncthreads();

    {
      const int b = tid >> 5;
      const int q = tid & 31;
      const f32x4 hv = *(const f32x4*)&h_f32[b][q*4];
      float p = hv[0]*hw4[0] + hv[1]*hw4[1] + hv[2]*hw4[2] + hv[3]*hw4[3];
      p += __shfl_xor(p, 1);  p += __shfl_xor(p, 2);  p += __shfl_xor(p, 4);
      p += __shfl_xor(p, 8);  p += __shfl_xor(p, 16);
      if (q == 0) D[(size_t)(batch0 + b) * T_ + ts] = p + hbv;
    }
  }
}

// W2 (k-major, f32) -> g_w2t (n-major, bf16), PRE-SWIZZLED within each row:
// elem k stored at k ^ ((n&7)<<3) so the linear LDS copy + swizzled ds_read
// is bank-even (rule: swizzle both sides or neither).
__global__ __launch_bounds__(256) void prep_w2t(const float* __restrict__ W2){
  const int idx = blockIdx.x * 256 + threadIdx.x;   // = n*512 + k
  const int n = idx >> 9;
  const int k = idx & 511;
  g_w2t[(n << 9) | (k ^ ((n & 7) << 3))] = f2bf(W2[(size_t)k * MH_ + n]);
}

// Fused MLP, LDS-staged GEMM:
// 512 blocks x 512 threads (8 waves). Block = 256 rows; wave = 32 rows
// (2 M-tiles, full-K A-frags in registers). N=512 in 8 passes of 64 cols;
// W2 pass-slice (64KB) double-buffered in LDS, shared by all waves; each
// B ds_read_b128 feeds 2 MFMAs. Staging reg-pipelined: loads for pass p+1
// issued right after the barrier, written to LDS next iteration.
__global__ __launch_bounds__(512, 2) void mlp_kernel(
    const float* __restrict__ Dbase,
    const float* __restrict__ W1, const float* __restrict__ b1,
    const float* __restrict__ b2, const float* __restrict__ W3,
    const float* __restrict__ b3, float* __restrict__ out)
{
  __shared__ __align__(16) unsigned short buf[2][64*512];   // 2 x 64KB

  const int tid = threadIdx.x;
  const int l   = tid & 63;
  const int c16 = l & 15;
  const int kb  = (l >> 4) * 8;
  const int w   = tid >> 6;
  const int m0  = blockIdx.x * 256 + w * 32;

  // A fragments for 2 M-tiles: h1[row][k], lane holds k = ks*32 + kb + i
  bf16x8 afr[2][16];
  #pragma unroll
  for (int mt = 0; mt < 2; ++mt){
    const int gr = m0 + mt*16 + c16;
    const float d1 = Dbase[gr];
    const float d2 = Dbase[BT_ + gr];
    const float d3 = Dbase[2*BT_ + gr];
    #pragma unroll
    for (int ks = 0; ks < 16; ++ks){
      const int kg = ks*32 + kb;
      f32x4 wa0 = *(const f32x4*)(W1 + kg);          f32x4 wa1 = *(const f32x4*)(W1 + kg + 4);
      f32x4 wb0 = *(const f32x4*)(W1 + MH_ + kg);    f32x4 wb1 = *(const f32x4*)(W1 + MH_ + kg + 4);
      f32x4 wc0 = *(const f32x4*)(W1 + 2*MH_ + kg);  f32x4 wc1 = *(const f32x4*)(W1 + 2*MH_ + kg + 4);
      f32x4 bv0 = *(const f32x4*)(b1 + kg);          f32x4 bv1 = *(const f32x4*)(b1 + kg + 4);
      union { unsigned short us[8]; bf16x8 v; } au;
      #pragma unroll
      for (int i = 0; i < 4; ++i){
        float v0 = bv0[i] + d1*wa0[i] + d2*wb0[i] + d3*wc0[i];
        float v1 = bv1[i] + d1*wa1[i] + d2*wb1[i] + d3*wc1[i];
        au.us[i]     = f2bf(fmaxf(v0, 0.f));
        au.us[4 + i] = f2bf(fmaxf(v1, 0.f));
      }
      afr[mt][ks] = au.v;
    }
  }

  // prologue: stage regs for pass 0 (g_w2t viewed as uint4; pass = 4096 uint4)
  const uint4* __restrict__ gsrc = (const uint4*)g_w2t;
  uint4 rg0, rg1, rg2, rg3, rg4, rg5, rg6, rg7;
  {
    const uint4* s = gsrc + tid;
    rg0 = s[0*512]; rg1 = s[1*512]; rg2 = s[2*512]; rg3 = s[3*512];
    rg4 = s[4*512]; rg5 = s[5*512]; rg6 = s[6*512]; rg7 = s[7*512];
  }

  float rs[2][4] = {{0.f,0.f,0.f,0.f},{0.f,0.f,0.f,0.f}};

  #pragma unroll 1
  for (int p = 0; p < 8; ++p){
    // write staged regs into this pass's buffer
    {
      uint4* bw = (uint4*)buf[p & 1] + tid;
      bw[0*512] = rg0; bw[1*512] = rg1; bw[2*512] = rg2; bw[3*512] = rg3;
      bw[4*512] = rg4; bw[5*512] = rg5; bw[6*512] = rg6; bw[7*512] = rg7;
    }
    __syncthreads();
    // issue next pass's loads (latency hidden under the MFMA phase)
    if (p < 7){
      const uint4* s = gsrc + (p + 1) * 4096 + tid;
      rg0 = s[0*512]; rg1 = s[1*512]; rg2 = s[2*512]; rg3 = s[3*512];
      rg4 = s[4*512]; rg5 = s[5*512]; rg6 = s[6*512]; rg7 = s[7*512];
    }

    const unsigned short* __restrict__ bb = buf[p & 1];
    f32x4 acc[2][4];
    #pragma unroll
    for (int nt = 0; nt < 4; ++nt){
      f32x4 z = {0.f,0.f,0.f,0.f};
      acc[0][nt] = z; acc[1][nt] = z;
    }
    #pragma unroll
    for (int ks = 0; ks < 16; ++ks){
      #pragma unroll
      for (int nt = 0; nt < 4; ++nt){
        const int nl = nt*16 + c16;
        const bf16x8 bfr =
          *(const bf16x8*)&bb[(nl << 9) | ((ks*32 + kb) ^ ((nl & 7) << 3))];
        acc[0][nt] = __builtin_amdgcn_mfma_f32_16x16x32_bf16(afr[0][ks], bfr, acc[0][nt], 0, 0, 0);
        acc[1][nt] = __builtin_amdgcn_mfma_f32_16x16x32_bf16(afr[1][ks], bfr, acc[1][nt], 0, 0, 0);
      }
    }
    #pragma unroll
    for (int nt = 0; nt < 4; ++nt){
      const int n = p*64 + nt*16 + c16;
      const float b2v = b2[n];
      const float w3v = W3[n];
      #pragma unroll
      for (int mt = 0; mt < 2; ++mt)
        #pragma unroll
        for (int r = 0; r < 4; ++r)
          rs[mt][r] += fmaxf(acc[mt][nt][r] + b2v, 0.f) * w3v;
    }
    __syncthreads();   // before next iteration's ds_write overwrites other buffer
  }

  // reduce across the 16 lanes (c16 bits) sharing the same C-rows
  #pragma unroll
  for (int mt = 0; mt < 2; ++mt){
    #pragma unroll
    for (int r = 0; r < 4; ++r){
      rs[mt][r] += __shfl_xor(rs[mt][r], 1);
      rs[mt][r] += __shfl_xor(rs[mt][r], 2);
      rs[mt][r] += __shfl_xor(rs[mt][r], 4);
      rs[mt][r] += __shfl_xor(rs[mt][r], 8);
    }
  }
  if (c16 == 0){
    const float bv = b3[0];
    #pragma unroll
    for (int mt = 0; mt < 2; ++mt){
      const int row = m0 + mt*16 + (l >> 4) * 4;
      #pragma unroll
      for (int r = 0; r < 4; ++r)
        out[3*BT_ + row + r] = rs[mt][r] + bv;
    }
  }
}

extern "C" void kernel_launch(void* const* d_in, const int* in_sizes, int n_in,
                              void* d_out, int out_size, void* d_ws, size_t ws_size,
                              hipStream_t stream){
  LstmArgs A;
  for (int i = 0; i < 3; ++i){
    A.x[i]    = (const float*)d_in[i];
    A.Wih[i]  = (const float*)d_in[3 + i*5 + 0];
    A.Whh[i]  = (const float*)d_in[3 + i*5 + 1];
    A.bias[i] = (const float*)d_in[3 + i*5 + 2];
    A.hw[i]   = (const float*)d_in[3 + i*5 + 3];
    A.hb[i]   = (const float*)d_in[3 + i*5 + 4];
  }
  A.out = (float*)d_out;

  prep_w2t<<<dim3(1024), dim3(256), 0, stream>>>((const float*)d_in[20]);
  prep_lstm<<<dim3(2048), dim3(256), 0, stream>>>(A);
  lstm_mfma_kernel<<<dim3(96), dim3(512), 0, stream>>>(A);
  mlp_kernel<<<dim3(512), dim3(512), 0, stream>>>((const float*)d_out,
      (const float*)d_in[18], (const float*)d_in[19],
      (const float*)d_in[21], (const float*)d_in[22], (const float*)d_in[23],
      (float*)d_out);
}

// Round 6
// 549.761 us; speedup vs baseline: 14.2662x; 1.0485x over previous
//
#include <hip/hip_runtime.h>

#define B_ 512
#define T_ 256
#define F_ 8
#define H_ 128
#define BT_ (B_*T_)
#define MH_ 512

typedef __attribute__((ext_vector_type(4))) float f32x4;
typedef __attribute__((ext_vector_type(8))) __bf16 bf16x8;

// Static device scratch
// g_w2t: W2^T bf16, row n holds k-elems PRE-SWIZZLED: elem (k ^ ((n&7)<<3)).
__device__ unsigned short g_w2t[MH_*MH_];
__device__ unsigned short g_whh[3][512][128];        // packed Whh bf16, [head][pc][k]
__device__ unsigned short g_wih[3][512][32];         // packed Wih bf16, k>=8 zero
__device__ unsigned short g_xbf[3][B_*T_*F_];        // x in bf16, same (B,T,F) layout

__device__ __forceinline__ unsigned short f2bf(float f){
  unsigned int u = __float_as_uint(f);
  unsigned int r = (u + 0x7FFFu + ((u >> 16) & 1u)) >> 16;  // RNE
  return (unsigned short)r;
}

// Clamp-free saturating gates: rcp(inf)=0 gives exact limits, no NaN path.
__device__ __forceinline__ float sigm(float x){
  return __builtin_amdgcn_rcpf(1.f + __expf(-x));
}
__device__ __forceinline__ float tanh_(float x){
  return 1.f - 2.f * __builtin_amdgcn_rcpf(__expf(2.f * x) + 1.f);
}

struct LstmArgs {
  const float* x[3];
  const float* Wih[3];
  const float* Whh[3];
  const float* bias[3];
  const float* hw[3];
  const float* hb[3];
  float* out;
};

// Pack Whh/Wih into MFMA column order + convert x to bf16.
__global__ __launch_bounds__(256) void prep_lstm(LstmArgs A){
  const int NW = 3*512*128;
  const int NI = 3*512*32;
  const int NX = 3*B_*T_*F_;
  for (int i = blockIdx.x*256 + threadIdx.x; i < NW+NI+NX; i += gridDim.x*256){
    if (i < NW){
      int head = i >> 16;
      int r = i & 65535;
      int pc = r >> 7, k = r & 127;
      int w = pc >> 6, g = (pc >> 4) & 3, s = pc & 15;
      int row = g*128 + w*16 + s;
      g_whh[head][pc][k] = f2bf(A.Whh[head][row*H_ + k]);
    } else if (i < NW + NI){
      int j = i - NW;
      int head = j >> 14;
      int r = j & 16383;
      int pc = r >> 5, k = r & 31;
      int w = pc >> 6, g = (pc >> 4) & 3, s = pc & 15;
      int row = g*128 + w*16 + s;
      g_wih[head][pc][k] = (k < 8) ? f2bf(A.Wih[head][row*F_ + k]) : (unsigned short)0;
    } else {
      int j = i - NW - NI;
      int head = j >> 20;
      int r = j & 1048575;
      g_xbf[head][r] = f2bf(A.x[head][r]);
    }
  }
}

// MFMA LSTM, latency-optimized recurrence:
//  - x(ts+1) prefetched into regs; x-MFMA accumulated LAST (h-MFMAs zero-init)
//  - h double-buffered in LDS -> ONE barrier per step
//  - head-dot partials from registers (4 shfl_xor) into part[2][16][8];
//    finalize by 128 threads after the barrier, overlapped with next step
__global__ __launch_bounds__(512) void lstm_mfma_kernel(LstmArgs A){
  const int head   = blockIdx.x >> 5;
  const int batch0 = (blockIdx.x & 31) * 16;
  const int tid = threadIdx.x;
  const int w   = tid >> 6;
  const int l   = tid & 63;
  const int c16 = l & 15;
  const int kb  = (l >> 4) * 8;

  const float* __restrict__ bs  = A.bias[head];
  const float* __restrict__ hwp = A.hw[head];
  const float hbv = A.hb[head][0];
  float* __restrict__ D = A.out + (size_t)head * BT_;

  // register-resident B-fragments
  bf16x8 bh[4][4];
  bf16x8 bx[4];
  #pragma unroll
  for (int g = 0; g < 4; ++g){
    const int pc = w*64 + g*16 + c16;
    #pragma unroll
    for (int kk = 0; kk < 4; ++kk)
      bh[g][kk] = *(const bf16x8*)&g_whh[head][pc][kk*32 + kb];
    bx[g] = *(const bf16x8*)&g_wih[head][pc][kb];
  }

  const int u = w*16 + c16;
  const float bi_ = bs[u], bf_ = bs[H_+u], bg_ = bs[2*H_+u], bo_ = bs[3*H_+u];
  const float hw_u = hwp[u];

  __shared__ __align__(16) unsigned short h_bf[2][16][136];
  __shared__ float part[2][16][8];

  for (int i = tid; i < 16*136; i += 512) ((unsigned short*)h_bf[0])[i] = 0;

  float cst[4] = {0.f, 0.f, 0.f, 0.f};
  const unsigned short* __restrict__ xrow =
      &g_xbf[head][(size_t)(batch0 + c16) * (T_*F_)];

  bf16x8 ax_cur = {};
  if (l < 16) ax_cur = *(const bf16x8*)(xrow);

  __syncthreads();

  int cur = 0;
  for (int ts = 0; ts < T_; ++ts){
    // A-frags for current h
    bf16x8 ah[4];
    #pragma unroll
    for (int kk = 0; kk < 4; ++kk)
      ah[kk] = *(const bf16x8*)&h_bf[cur][c16][kk*32 + kb];

    // prefetch next step's x (off the critical path)
    bf16x8 ax_nxt = {};
    {
      const int tn = (ts + 1 < T_) ? ts + 1 : ts;
      if (l < 16) ax_nxt = *(const bf16x8*)(xrow + tn*F_);
    }

    // h-MFMAs first (zero init), x-MFMA last
    f32x4 acc[4];
    const f32x4 z4 = {0.f, 0.f, 0.f, 0.f};
    #pragma unroll
    for (int g = 0; g < 4; ++g)
      acc[g] = __builtin_amdgcn_mfma_f32_16x16x32_bf16(ah[0], bh[g][0], z4, 0, 0, 0);
    #pragma unroll
    for (int kk = 1; kk < 4; ++kk){
      #pragma unroll
      for (int g = 0; g < 4; ++g)
        acc[g] = __builtin_amdgcn_mfma_f32_16x16x32_bf16(ah[kk], bh[g][kk], acc[g], 0, 0, 0);
    }
    #pragma unroll
    for (int g = 0; g < 4; ++g)
      acc[g] = __builtin_amdgcn_mfma_f32_16x16x32_bf16(ax_cur, bx[g], acc[g], 0, 0, 0);

    // cell update + head-dot partial (registers only)
    float p[4];
    #pragma unroll
    for (int r = 0; r < 4; ++r){
      const float Zi = acc[0][r] + bi_;
      const float Zf = acc[1][r] + bf_;
      const float Zg = acc[2][r] + bg_;
      const float Zo = acc[3][r] + bo_;
      cst[r] = sigm(Zf) * cst[r] + sigm(Zi) * tanh_(Zg);
      const float hnr = sigm(Zo) * tanh_(cst[r]);
      h_bf[cur ^ 1][(l >> 4)*4 + r][u] = f2bf(hnr);
      p[r] = hnr * hw_u;
    }
    // reduce over the 16 units this wave owns (lane bits 0-3)
    #pragma unroll
    for (int r = 0; r < 4; ++r){
      p[r] += __shfl_xor(p[r], 1);
      p[r] += __shfl_xor(p[r], 2);
      p[r] += __shfl_xor(p[r], 4);
      p[r] += __shfl_xor(p[r], 8);
    }
    if (c16 == 0){
      #pragma unroll
      for (int r = 0; r < 4; ++r)
        part[cur][(l >> 4)*4 + r][w] = p[r];
    }

    __syncthreads();                       // new h + partials visible

    // finalize head-dot for step ts (overlaps next step's MFMA phase)
    if (tid < 128){
      const int b  = tid >> 3;
      const int wv = tid & 7;
      float v = part[cur][b][wv];
      v += __shfl_xor(v, 1);
      v += __shfl_xor(v, 2);
      v += __shfl_xor(v, 4);
      if (wv == 0) D[(size_t)(batch0 + b) * T_ + ts] = v + hbv;
    }

    ax_cur = ax_nxt;
    cur ^= 1;
  }
}

// W2 (k-major, f32) -> g_w2t (n-major, bf16), pre-swizzled within each row.
__global__ __launch_bounds__(256) void prep_w2t(const float* __restrict__ W2){
  const int idx = blockIdx.x * 256 + threadIdx.x;   // = n*512 + k
  const int n = idx >> 9;
  const int k = idx & 511;
  g_w2t[(n << 9) | (k ^ ((n & 7) << 3))] = f2bf(W2[(size_t)k * MH_ + n]);
}

// Fused MLP, LDS-staged GEMM (round-5 structure; b2/W3 loads hoisted early).
__global__ __launch_bounds__(512, 2) void mlp_kernel(
    const float* __restrict__ Dbase,
    const float* __restrict__ W1, const float* __restrict__ b1,
    const float* __restrict__ b2, const float* __restrict__ W3,
    const float* __restrict__ b3, float* __restrict__ out)
{
  __shared__ __align__(16) unsigned short buf[2][64*512];   // 2 x 64KB

  const int tid = threadIdx.x;
  const int l   = tid & 63;
  const int c16 = l & 15;
  const int kb  = (l >> 4) * 8;
  const int w   = tid >> 6;
  const int m0  = blockIdx.x * 256 + w * 32;

  // A fragments for 2 M-tiles
  bf16x8 afr[2][16];
  #pragma unroll
  for (int mt = 0; mt < 2; ++mt){
    const int gr = m0 + mt*16 + c16;
    const float d1 = Dbase[gr];
    const float d2 = Dbase[BT_ + gr];
    const float d3 = Dbase[2*BT_ + gr];
    #pragma unroll
    for (int ks = 0; ks < 16; ++ks){
      const int kg = ks*32 + kb;
      f32x4 wa0 = *(const f32x4*)(W1 + kg);          f32x4 wa1 = *(const f32x4*)(W1 + kg + 4);
      f32x4 wb0 = *(const f32x4*)(W1 + MH_ + kg);    f32x4 wb1 = *(const f32x4*)(W1 + MH_ + kg + 4);
      f32x4 wc0 = *(const f32x4*)(W1 + 2*MH_ + kg);  f32x4 wc1 = *(const f32x4*)(W1 + 2*MH_ + kg + 4);
      f32x4 bv0 = *(const f32x4*)(b1 + kg);          f32x4 bv1 = *(const f32x4*)(b1 + kg + 4);
      union { unsigned short us[8]; bf16x8 v; } au;
      #pragma unroll
      for (int i = 0; i < 4; ++i){
        float v0 = bv0[i] + d1*wa0[i] + d2*wb0[i] + d3*wc0[i];
        float v1 = bv1[i] + d1*wa1[i] + d2*wb1[i] + d3*wc1[i];
        au.us[i]     = f2bf(fmaxf(v0, 0.f));
        au.us[4 + i] = f2bf(fmaxf(v1, 0.f));
      }
      afr[mt][ks] = au.v;
    }
  }

  const uint4* __restrict__ gsrc = (const uint4*)g_w2t;
  uint4 rg0, rg1, rg2, rg3, rg4, rg5, rg6, rg7;
  {
    const uint4* s = gsrc + tid;
    rg0 = s[0*512]; rg1 = s[1*512]; rg2 = s[2*512]; rg3 = s[3*512];
    rg4 = s[4*512]; rg5 = s[5*512]; rg6 = s[6*512]; rg7 = s[7*512];
  }

  float rs[2][4] = {{0.f,0.f,0.f,0.f},{0.f,0.f,0.f,0.f}};

  #pragma unroll 1
  for (int p = 0; p < 8; ++p){
    {
      uint4* bw = (uint4*)buf[p & 1] + tid;
      bw[0*512] = rg0; bw[1*512] = rg1; bw[2*512] = rg2; bw[3*512] = rg3;
      bw[4*512] = rg4; bw[5*512] = rg5; bw[6*512] = rg6; bw[7*512] = rg7;
    }
    __syncthreads();
    if (p < 7){
      const uint4* s = gsrc + (p + 1) * 4096 + tid;
      rg0 = s[0*512]; rg1 = s[1*512]; rg2 = s[2*512]; rg3 = s[3*512];
      rg4 = s[4*512]; rg5 = s[5*512]; rg6 = s[6*512]; rg7 = s[7*512];
    }
    // epilogue constants issued early; land under the MFMA phase
    float b2v[4], w3v[4];
    #pragma unroll
    for (int nt = 0; nt < 4; ++nt){
      const int n = p*64 + nt*16 + c16;
      b2v[nt] = b2[n];
      w3v[nt] = W3[n];
    }

    const unsigned short* __restrict__ bb = buf[p & 1];
    f32x4 acc[2][4];
    #pragma unroll
    for (int nt = 0; nt < 4; ++nt){
      f32x4 z = {0.f,0.f,0.f,0.f};
      acc[0][nt] = z; acc[1][nt] = z;
    }
    #pragma unroll
    for (int ks = 0; ks < 16; ++ks){
      #pragma unroll
      for (int nt = 0; nt < 4; ++nt){
        const int nl = nt*16 + c16;
        const bf16x8 bfr =
          *(const bf16x8*)&bb[(nl << 9) | ((ks*32 + kb) ^ ((nl & 7) << 3))];
        acc[0][nt] = __builtin_amdgcn_mfma_f32_16x16x32_bf16(afr[0][ks], bfr, acc[0][nt], 0, 0, 0);
        acc[1][nt] = __builtin_amdgcn_mfma_f32_16x16x32_bf16(afr[1][ks], bfr, acc[1][nt], 0, 0, 0);
      }
    }
    #pragma unroll
    for (int nt = 0; nt < 4; ++nt){
      #pragma unroll
      for (int mt = 0; mt < 2; ++mt)
        #pragma unroll
        for (int r = 0; r < 4; ++r)
          rs[mt][r] += fmaxf(acc[mt][nt][r] + b2v[nt], 0.f) * w3v[nt];
    }
    __syncthreads();
  }

  #pragma unroll
  for (int mt = 0; mt < 2; ++mt){
    #pragma unroll
    for (int r = 0; r < 4; ++r){
      rs[mt][r] += __shfl_xor(rs[mt][r], 1);
      rs[mt][r] += __shfl_xor(rs[mt][r], 2);
      rs[mt][r] += __shfl_xor(rs[mt][r], 4);
      rs[mt][r] += __shfl_xor(rs[mt][r], 8);
    }
  }
  if (c16 == 0){
    const float bv = b3[0];
    #pragma unroll
    for (int mt = 0; mt < 2; ++mt){
      const int row = m0 + mt*16 + (l >> 4) * 4;
      #pragma unroll
      for (int r = 0; r < 4; ++r)
        out[3*BT_ + row + r] = rs[mt][r] + bv;
    }
  }
}

extern "C" void kernel_launch(void* const* d_in, const int* in_sizes, int n_in,
                              void* d_out, int out_size, void* d_ws, size_t ws_size,
                              hipStream_t stream){
  LstmArgs A;
  for (int i = 0; i < 3; ++i){
    A.x[i]    = (const float*)d_in[i];
    A.Wih[i]  = (const float*)d_in[3 + i*5 + 0];
    A.Whh[i]  = (const float*)d_in[3 + i*5 + 1];
    A.bias[i] = (const float*)d_in[3 + i*5 + 2];
    A.hw[i]   = (const float*)d_in[3 + i*5 + 3];
    A.hb[i]   = (const float*)d_in[3 + i*5 + 4];
  }
  A.out = (float*)d_out;

  prep_w2t<<<dim3(1024), dim3(256), 0, stream>>>((const float*)d_in[20]);
  prep_lstm<<<dim3(2048), dim3(256), 0, stream>>>(A);
  lstm_mfma_kernel<<<dim3(96), dim3(512), 0, stream>>>(A);
  mlp_kernel<<<dim3(512), dim3(512), 0, stream>>>((const float*)d_out,
      (const float*)d_in[18], (const float*)d_in[19],
      (const float*)d_in[21], (const float*)d_in[22], (const float*)d_in[23],
      (float*)d_out);
}

// Round 7
// 471.796 us; speedup vs baseline: 16.6238x; 1.1653x over previous
//
#include <hip/hip_runtime.h>

#define B_ 512
#define T_ 256
#define F_ 8
#define H_ 128
#define BT_ (B_*T_)
#define MH_ 512
#define L2E 1.4426950408889634f

typedef __attribute__((ext_vector_type(4))) float f32x4;
typedef __attribute__((ext_vector_type(8))) __bf16 bf16x8;

// Static device scratch
// g_w2t: W2^T bf16, row n holds k-elems PRE-SWIZZLED: elem (k ^ ((n&7)<<3)).
__device__ unsigned short g_w2t[MH_*MH_];
// packed Whh/Wih bf16, [head][pc][k], PRE-SCALED: i,f,o rows by -log2e, g rows by +2log2e
__device__ unsigned short g_whh[3][512][128];
__device__ unsigned short g_wih[3][512][32];
__device__ unsigned short g_xbf[3][B_*T_*F_];        // x in bf16, same (B,T,F) layout

__device__ __forceinline__ unsigned short f2bf(float f){
  unsigned int u = __float_as_uint(f);
  unsigned int r = (u + 0x7FFFu + ((u >> 16) & 1u)) >> 16;  // RNE
  return (unsigned short)r;
}

#if __has_builtin(__builtin_amdgcn_exp2f)
#define EXP2F __builtin_amdgcn_exp2f
#else
#define EXP2F exp2f
#endif
#define RCPF __builtin_amdgcn_rcpf

struct LstmArgs {
  const float* x[3];
  const float* Wih[3];
  const float* Whh[3];
  const float* bias[3];
  const float* hw[3];
  const float* hb[3];
  float* out;
};

// Pack Whh/Wih into MFMA column order (pre-scaled by +-log2e) + x to bf16.
__global__ __launch_bounds__(256) void prep_lstm(LstmArgs A){
  const int NW = 3*512*128;
  const int NI = 3*512*32;
  const int NX = 3*B_*T_*F_;
  for (int i = blockIdx.x*256 + threadIdx.x; i < NW+NI+NX; i += gridDim.x*256){
    if (i < NW){
      int head = i >> 16;
      int r = i & 65535;
      int pc = r >> 7, k = r & 127;
      int w = pc >> 6, g = (pc >> 4) & 3, s = pc & 15;
      int row = g*128 + w*16 + s;
      float sc = (g == 2) ? (2.0f*L2E) : (-L2E);
      g_whh[head][pc][k] = f2bf(A.Whh[head][row*H_ + k] * sc);
    } else if (i < NW + NI){
      int j = i - NW;
      int head = j >> 14;
      int r = j & 16383;
      int pc = r >> 5, k = r & 31;
      int w = pc >> 6, g = (pc >> 4) & 3, s = pc & 15;
      int row = g*128 + w*16 + s;
      float sc = (g == 2) ? (2.0f*L2E) : (-L2E);
      g_wih[head][pc][k] = (k < 8) ? f2bf(A.Wih[head][row*F_ + k] * sc) : (unsigned short)0;
    } else {
      int j = i - NW - NI;
      int head = j >> 20;
      int r = j & 1048575;
      g_xbf[head][r] = f2bf(A.x[head][r]);
    }
  }
}

// MFMA LSTM, 8-batch tiles with row-spread mapping:
//  batch b (0..7) lives at A/C row (b>>1)*4+(b&1) -> every lane owns C regs
//  r=0,1 only => 2 cells/lane. Gates use exp2 with weights pre-scaled by log2e.
//  Head-dot p is shfl-reduced one step LATE (overlaps MFMA), finalized after
//  the barrier. One barrier per step; h double-buffered in LDS.
__global__ __launch_bounds__(512) void lstm_mfma_kernel(LstmArgs A){
  const int head   = blockIdx.x >> 6;          // 64 tiles per head, 192 blocks
  const int batch0 = (blockIdx.x & 63) * 8;
  const int tid = threadIdx.x;
  const int w   = tid >> 6;
  const int l   = tid & 63;
  const int c16 = l & 15;
  const int kb  = (l >> 4) * 8;

  const float* __restrict__ bs  = A.bias[head];
  const float* __restrict__ hwp = A.hw[head];
  const float hbv = A.hb[head][0];
  float* __restrict__ D = A.out + (size_t)head * BT_;

  // register-resident B-fragments
  bf16x8 bh[4][4];
  bf16x8 bx[4];
  #pragma unroll
  for (int g = 0; g < 4; ++g){
    const int pc = w*64 + g*16 + c16;
    #pragma unroll
    for (int kk = 0; kk < 4; ++kk)
      bh[g][kk] = *(const bf16x8*)&g_whh[head][pc][kk*32 + kb];
    bx[g] = *(const bf16x8*)&g_wih[head][pc][kb];
  }

  const int u = w*16 + c16;
  const float bi_ = bs[u]        * (-L2E);
  const float bf_ = bs[H_+u]     * (-L2E);
  const float bg_ = bs[2*H_+u]   * (2.0f*L2E);
  const float bo_ = bs[3*H_+u]   * (-L2E);
  const float hw_u = hwp[u];

  __shared__ __align__(16) unsigned short h_bf[2][16][132];
  __shared__ float part[2][8][8];

  for (int i = tid; i < 2*16*132; i += 512) ((unsigned short*)h_bf)[i] = 0;

  float cst[2] = {0.f, 0.f};
  float pp[2]  = {0.f, 0.f};

  // x A-row mapping: lane c16 supplies A-row c16; valid rows {0,1,4,5,8,9,12,13}
  const int bt = ((c16 >> 2) << 1) | (c16 & 1);          // batch-in-tile for row c16
  const bool xvalid = (l < 16) && !(l & 2);
  const unsigned short* __restrict__ xrow =
      &g_xbf[head][(size_t)(batch0 + bt) * (T_*F_)];

  bf16x8 ax_cur = {};
  if (xvalid) ax_cur = *(const bf16x8*)(xrow);

  __syncthreads();

  int cur = 0;
  for (int ts = 0; ts < T_; ++ts){
    // A-frags for current h
    bf16x8 ah[4];
    #pragma unroll
    for (int kk = 0; kk < 4; ++kk)
      ah[kk] = *(const bf16x8*)&h_bf[cur][c16][kk*32 + kb];

    // prefetch next step's x (off the critical path)
    bf16x8 ax_nxt = {};
    {
      const int tn = (ts + 1 < T_) ? ts + 1 : ts;
      if (xvalid) ax_nxt = *(const bf16x8*)(xrow + tn*F_);
    }

    // h-MFMAs first (zero init), x-MFMA last
    f32x4 acc[4];
    const f32x4 z4 = {0.f, 0.f, 0.f, 0.f};
    #pragma unroll
    for (int g = 0; g < 4; ++g)
      acc[g] = __builtin_amdgcn_mfma_f32_16x16x32_bf16(ah[0], bh[g][0], z4, 0, 0, 0);
    #pragma unroll
    for (int kk = 1; kk < 4; ++kk){
      #pragma unroll
      for (int g = 0; g < 4; ++g)
        acc[g] = __builtin_amdgcn_mfma_f32_16x16x32_bf16(ah[kk], bh[g][kk], acc[g], 0, 0, 0);
    }
    #pragma unroll
    for (int g = 0; g < 4; ++g)
      acc[g] = __builtin_amdgcn_mfma_f32_16x16x32_bf16(ax_cur, bx[g], acc[g], 0, 0, 0);

    // previous step's head-dot reduction (DS pipe; overlaps MFMA execution)
    if (ts > 0){
      #pragma unroll
      for (int r = 0; r < 2; ++r){
        float v = pp[r];
        v += __shfl_xor(v, 1); v += __shfl_xor(v, 2);
        v += __shfl_xor(v, 4); v += __shfl_xor(v, 8);
        if (c16 == 0) part[(ts-1) & 1][(l >> 4)*2 + r][w] = v;
      }
    }

    // cell update: 2 cells/lane (regs r=0,1), exp2-form gates
    #pragma unroll
    for (int r = 0; r < 2; ++r){
      const float Zi = acc[0][r] + bi_;
      const float Zf = acc[1][r] + bf_;
      const float Zg = acc[2][r] + bg_;
      const float Zo = acc[3][r] + bo_;
      const float si = RCPF(1.f + EXP2F(Zi));
      const float sf = RCPF(1.f + EXP2F(Zf));
      const float tg = 1.f - 2.f * RCPF(EXP2F(Zg) + 1.f);
      const float so = RCPF(1.f + EXP2F(Zo));
      cst[r] = sf * cst[r] + si * tg;
      const float tc = 1.f - 2.f * RCPF(EXP2F(cst[r] * (2.0f*L2E)) + 1.f);
      const float hnr = so * tc;
      h_bf[cur ^ 1][(l >> 4)*4 + r][u] = f2bf(hnr);
      pp[r] = hnr * hw_u;                       // consumed next iteration
    }

    __syncthreads();                            // new h + part visible

    // finalize D for step ts-1 (wave 0 only; overlaps other waves' next step)
    if (ts > 0 && tid < 64){
      const int b  = tid >> 3;
      const int wv = tid & 7;
      float v = part[(ts-1) & 1][b][wv];
      v += __shfl_xor(v, 1); v += __shfl_xor(v, 2); v += __shfl_xor(v, 4);
      if (wv == 0) D[(size_t)(batch0 + b) * T_ + (ts-1)] = v + hbv;
    }

    ax_cur = ax_nxt;
    cur ^= 1;
  }

  // epilogue: step T-1's head-dot
  #pragma unroll
  for (int r = 0; r < 2; ++r){
    float v = pp[r];
    v += __shfl_xor(v, 1); v += __shfl_xor(v, 2);
    v += __shfl_xor(v, 4); v += __shfl_xor(v, 8);
    if (c16 == 0) part[(T_-1) & 1][(l >> 4)*2 + r][w] = v;
  }
  __syncthreads();
  if (tid < 64){
    const int b  = tid >> 3;
    const int wv = tid & 7;
    float v = part[(T_-1) & 1][b][wv];
    v += __shfl_xor(v, 1); v += __shfl_xor(v, 2); v += __shfl_xor(v, 4);
    if (wv == 0) D[(size_t)(batch0 + b) * T_ + (T_-1)] = v + hbv;
  }
}

// W2 (k-major, f32) -> g_w2t (n-major, bf16), pre-swizzled within each row.
__global__ __launch_bounds__(256) void prep_w2t(const float* __restrict__ W2){
  const int idx = blockIdx.x * 256 + threadIdx.x;   // = n*512 + k
  const int n = idx >> 9;
  const int k = idx & 511;
  g_w2t[(n << 9) | (k ^ ((n & 7) << 3))] = f2bf(W2[(size_t)k * MH_ + n]);
}

// Fused MLP, LDS-staged GEMM (unchanged from round 6).
__global__ __launch_bounds__(512, 2) void mlp_kernel(
    const float* __restrict__ Dbase,
    const float* __restrict__ W1, const float* __restrict__ b1,
    const float* __restrict__ b2, const float* __restrict__ W3,
    const float* __restrict__ b3, float* __restrict__ out)
{
  __shared__ __align__(16) unsigned short buf[2][64*512];   // 2 x 64KB

  const int tid = threadIdx.x;
  const int l   = tid & 63;
  const int c16 = l & 15;
  const int kb  = (l >> 4) * 8;
  const int w   = tid >> 6;
  const int m0  = blockIdx.x * 256 + w * 32;

  // A fragments for 2 M-tiles
  bf16x8 afr[2][16];
  #pragma unroll
  for (int mt = 0; mt < 2; ++mt){
    const int gr = m0 + mt*16 + c16;
    const float d1 = Dbase[gr];
    const float d2 = Dbase[BT_ + gr];
    const float d3 = Dbase[2*BT_ + gr];
    #pragma unroll
    for (int ks = 0; ks < 16; ++ks){
      const int kg = ks*32 + kb;
      f32x4 wa0 = *(const f32x4*)(W1 + kg);          f32x4 wa1 = *(const f32x4*)(W1 + kg + 4);
      f32x4 wb0 = *(const f32x4*)(W1 + MH_ + kg);    f32x4 wb1 = *(const f32x4*)(W1 + MH_ + kg + 4);
      f32x4 wc0 = *(const f32x4*)(W1 + 2*MH_ + kg);  f32x4 wc1 = *(const f32x4*)(W1 + 2*MH_ + kg + 4);
      f32x4 bv0 = *(const f32x4*)(b1 + kg);          f32x4 bv1 = *(const f32x4*)(b1 + kg + 4);
      union { unsigned short us[8]; bf16x8 v; } au;
      #pragma unroll
      for (int i = 0; i < 4; ++i){
        float v0 = bv0[i] + d1*wa0[i] + d2*wb0[i] + d3*wc0[i];
        float v1 = bv1[i] + d1*wa1[i] + d2*wb1[i] + d3*wc1[i];
        au.us[i]     = f2bf(fmaxf(v0, 0.f));
        au.us[4 + i] = f2bf(fmaxf(v1, 0.f));
      }
      afr[mt][ks] = au.v;
    }
  }

  const uint4* __restrict__ gsrc = (const uint4*)g_w2t;
  uint4 rg0, rg1, rg2, rg3, rg4, rg5, rg6, rg7;
  {
    const uint4* s = gsrc + tid;
    rg0 = s[0*512]; rg1 = s[1*512]; rg2 = s[2*512]; rg3 = s[3*512];
    rg4 = s[4*512]; rg5 = s[5*512]; rg6 = s[6*512]; rg7 = s[7*512];
  }

  float rs[2][4] = {{0.f,0.f,0.f,0.f},{0.f,0.f,0.f,0.f}};

  #pragma unroll 1
  for (int p = 0; p < 8; ++p){
    {
      uint4* bw = (uint4*)buf[p & 1] + tid;
      bw[0*512] = rg0; bw[1*512] = rg1; bw[2*512] = rg2; bw[3*512] = rg3;
      bw[4*512] = rg4; bw[5*512] = rg5; bw[6*512] = rg6; bw[7*512] = rg7;
    }
    __syncthreads();
    if (p < 7){
      const uint4* s = gsrc + (p + 1) * 4096 + tid;
      rg0 = s[0*512]; rg1 = s[1*512]; rg2 = s[2*512]; rg3 = s[3*512];
      rg4 = s[4*512]; rg5 = s[5*512]; rg6 = s[6*512]; rg7 = s[7*512];
    }
    // epilogue constants issued early; land under the MFMA phase
    float b2v[4], w3v[4];
    #pragma unroll
    for (int nt = 0; nt < 4; ++nt){
      const int n = p*64 + nt*16 + c16;
      b2v[nt] = b2[n];
      w3v[nt] = W3[n];
    }

    const unsigned short* __restrict__ bb = buf[p & 1];
    f32x4 acc[2][4];
    #pragma unroll
    for (int nt = 0; nt < 4; ++nt){
      f32x4 z = {0.f,0.f,0.f,0.f};
      acc[0][nt] = z; acc[1][nt] = z;
    }
    #pragma unroll
    for (int ks = 0; ks < 16; ++ks){
      #pragma unroll
      for (int nt = 0; nt < 4; ++nt){
        const int nl = nt*16 + c16;
        const bf16x8 bfr =
          *(const bf16x8*)&bb[(nl << 9) | ((ks*32 + kb) ^ ((nl & 7) << 3))];
        acc[0][nt] = __builtin_amdgcn_mfma_f32_16x16x32_bf16(afr[0][ks], bfr, acc[0][nt], 0, 0, 0);
        acc[1][nt] = __builtin_amdgcn_mfma_f32_16x16x32_bf16(afr[1][ks], bfr, acc[1][nt], 0, 0, 0);
      }
    }
    #pragma unroll
    for (int nt = 0; nt < 4; ++nt){
      #pragma unroll
      for (int mt = 0; mt < 2; ++mt)
        #pragma unroll
        for (int r = 0; r < 4; ++r)
          rs[mt][r] += fmaxf(acc[mt][nt][r] + b2v[nt], 0.f) * w3v[nt];
    }
    __syncthreads();
  }

  #pragma unroll
  for (int mt = 0; mt < 2; ++mt){
    #pragma unroll
    for (int r = 0; r < 4; ++r){
      rs[mt][r] += __shfl_xor(rs[mt][r], 1);
      rs[mt][r] += __shfl_xor(rs[mt][r], 2);
      rs[mt][r] += __shfl_xor(rs[mt][r], 4);
      rs[mt][r] += __shfl_xor(rs[mt][r], 8);
    }
  }
  if (c16 == 0){
    const float bv = b3[0];
    #pragma unroll
    for (int mt = 0; mt < 2; ++mt){
      const int row = m0 + mt*16 + (l >> 4) * 4;
      #pragma unroll
      for (int r = 0; r < 4; ++r)
        out[3*BT_ + row + r] = rs[mt][r] + bv;
    }
  }
}

extern "C" void kernel_launch(void* const* d_in, const int* in_sizes, int n_in,
                              void* d_out, int out_size, void* d_ws, size_t ws_size,
                              hipStream_t stream){
  LstmArgs A;
  for (int i = 0; i < 3; ++i){
    A.x[i]    = (const float*)d_in[i];
    A.Wih[i]  = (const float*)d_in[3 + i*5 + 0];
    A.Whh[i]  = (const float*)d_in[3 + i*5 + 1];
    A.bias[i] = (const float*)d_in[3 + i*5 + 2];
    A.hw[i]   = (const float*)d_in[3 + i*5 + 3];
    A.hb[i]   = (const float*)d_in[3 + i*5 + 4];
  }
  A.out = (float*)d_out;

  prep_w2t<<<dim3(1024), dim3(256), 0, stream>>>((const float*)d_in[20]);
  prep_lstm<<<dim3(2048), dim3(256), 0, stream>>>(A);
  lstm_mfma_kernel<<<dim3(192), dim3(512), 0, stream>>>(A);
  mlp_kernel<<<dim3(512), dim3(512), 0, stream>>>((const float*)d_out,
      (const float*)d_in[18], (const float*)d_in[19],
      (const float*)d_in[21], (const float*)d_in[22], (const float*)d_in[23],
      (float*)d_out);
}